// Round 4
// baseline (1968.273 us; speedup 1.0000x reference)
//
#include <hip/hip_runtime.h>
#include <hip/hip_bf16.h>
#include <cstdint>

#define BB 16384
// EMBED 1536, DETER 1024, STOC 32, HID 1024, ACT 12, DIST 64

typedef __attribute__((ext_vector_type(8))) short short8;
typedef __attribute__((ext_vector_type(4))) float f32x4;

__device__ __forceinline__ unsigned short f2bf(float x) {
    uint32_t u = __float_as_uint(x);
    u += 0x7FFFu + ((u >> 16) & 1u);
    return (unsigned short)(u >> 16);
}
__device__ __forceinline__ float bf2f(unsigned short b) {
    return __uint_as_float(((uint32_t)b) << 16);
}
__device__ __forceinline__ void split2(float x, unsigned short* hi, unsigned short* lo) {
    unsigned short h = f2bf(x);
    *hi = h;
    *lo = f2bf(x - bf2f(h));
}

#define GLL(gp, lp) __builtin_amdgcn_global_load_lds( \
    (const __attribute__((address_space(1))) void*)(gp), \
    (__attribute__((address_space(3))) void*)(lp), 16, 0, 0)

// ---------------------------------------------------------------------------
// Split/convert kernels (fp32 -> bf16 hi/lo pairs)
// ---------------------------------------------------------------------------

// sa = [stoc*mask | action | 0pad] -> [Bc,64]  (pointers pre-offset to chunk)
__global__ __launch_bounds__(256) void split_sa(
    const float* __restrict__ stoc, const float* __restrict__ action,
    const float* __restrict__ mask,
    unsigned short* __restrict__ hi, unsigned short* __restrict__ lo) {
    int tid = threadIdx.x;
    int r = blockIdx.x * 4 + (tid >> 6);
    int c = tid & 63;
    float v = 0.f;
    if (c < 32) v = stoc[(size_t)r * 32 + c] * mask[r];
    else if (c < 44) v = action[(size_t)r * 12 + (c - 32)];
    size_t o = (size_t)r * 64 + c;
    unsigned short h, l; split2(v, &h, &l);
    hi[o] = h; lo[o] = l;
}

// w_pre [1024,44] -> [1024,64] zero-padded
__global__ __launch_bounds__(256) void split_wpre(
    const float* __restrict__ w, unsigned short* __restrict__ hi, unsigned short* __restrict__ lo) {
    int idx = blockIdx.x * 256 + threadIdx.x; // < 65536
    int row = idx >> 6, c = idx & 63;
    float v = (c < 44) ? w[row * 44 + c] : 0.f;
    unsigned short h, l; split2(v, &h, &l);
    hi[idx] = h; lo[idx] = l;
}

// merged flat float4 split of the 4 big weights (segments in blocks):
// [0,3072) w_ih, [3072,6144) w_hh, [6144,7168) wp1, [7168,9728) wq1
__global__ __launch_bounds__(256) void split_weights(
    const float* __restrict__ w0, unsigned short* __restrict__ h0, unsigned short* __restrict__ l0,
    const float* __restrict__ w1, unsigned short* __restrict__ h1, unsigned short* __restrict__ l1,
    const float* __restrict__ w2, unsigned short* __restrict__ h2, unsigned short* __restrict__ l2,
    const float* __restrict__ w3, unsigned short* __restrict__ h3, unsigned short* __restrict__ l3) {
    int b = blockIdx.x;
    const float* src; unsigned short* hi; unsigned short* lo; int lb;
    if (b < 3072)      { src = w0; hi = h0; lo = l0; lb = b; }
    else if (b < 6144) { src = w1; hi = h1; lo = l1; lb = b - 3072; }
    else if (b < 7168) { src = w2; hi = h2; lo = l2; lb = b - 6144; }
    else               { src = w3; hi = h3; lo = l3; lb = b - 7168; }
    size_t i4 = (size_t)lb * 256 + threadIdx.x;
    float4 v = ((const float4*)src)[i4];
    ushort4 h, l;
    split2(v.x, &h.x, &l.x);
    split2(v.y, &h.y, &l.y);
    split2(v.z, &h.z, &l.z);
    split2(v.w, &h.w, &l.w);
    ((ushort4*)hi)[i4] = h;
    ((ushort4*)lo)[i4] = l;
}

// embedding [Bc,1536] -> he[:, 1024:2560]  (e pre-offset)
__global__ __launch_bounds__(256) void split_embed(
    const float* __restrict__ e, unsigned short* __restrict__ hi, unsigned short* __restrict__ lo) {
    int b = blockIdx.y;
    int c = blockIdx.x * 256 + threadIdx.x; // < 1536
    float v = e[(size_t)b * 1536 + c];
    size_t o = (size_t)b * 2560 + 1024 + c;
    unsigned short h, l; split2(v, &h, &l);
    hi[o] = h; lo[o] = l;
}

// deter*mask [Bc,1024] -> dh/dl  (pointers pre-offset)
__global__ __launch_bounds__(256) void split_deter(
    const float* __restrict__ dt, const float* __restrict__ mask,
    unsigned short* __restrict__ hi, unsigned short* __restrict__ lo) {
    int b = blockIdx.y;
    int c = blockIdx.x * 256 + threadIdx.x; // < 1024
    float v = dt[(size_t)b * 1024 + c] * mask[b];
    size_t o = (size_t)b * 1024 + c;
    unsigned short h, l; split2(v, &h, &l);
    hi[o] = h; lo[o] = l;
}

// ---------------------------------------------------------------------------
// Split-bf16 MFMA GEMM: C[M,N] = act(A[M,K] @ B[N,K]^T + bias [+ C_prev])
// A,B as hi/lo bf16. 128x128 tile, BK=32, 4 waves (2x2), 4x4 frags of
// 16x16x32. 3-product scheme: C = Ah*Bh + Ah*Bl + Al*Bh (rel err ~2^-18).
//
// LDS tile [128][32] elems (64B rows): T2 involution swizzle applied to BOTH
// the global source col and the LDS read col (rule 21; gload_lds is linear):
//   physical slot = logical slot ^ ((row>>1)&3)  -> max 2-way conflict (free)
//
// ACC=1: epilogue reads Cf and accumulates (RMW; unique (row,col) per thread).
// Grid: 1D nbm*nbn, cta-swizzle groups of gm m-blocks (nbm % gm == 0).
// ---------------------------------------------------------------------------
template<int RELU, int BF16OUT, int ACC>
__global__ __launch_bounds__(256, 3) void gemm_hl(
    const unsigned short* __restrict__ Ahi, const unsigned short* __restrict__ Alo, int lda,
    const unsigned short* __restrict__ Bhi, const unsigned short* __restrict__ Blo, int ldb,
    const float* __restrict__ bias,
    float* __restrict__ Cf, unsigned short* __restrict__ Chi, unsigned short* __restrict__ Clo,
    int ldc, int K, int nbn, int gm) {
    __shared__ unsigned short lsAh[128 * 32], lsAl[128 * 32];
    __shared__ unsigned short lsBh[128 * 32], lsBl[128 * 32];

    const int tid = threadIdx.x;
    const int wave = tid >> 6, lane = tid & 63;

    int bid = blockIdx.x;
    int group = bid / (gm * nbn);
    int rem = bid % (gm * nbn);
    int bm = group * gm + (rem % gm);
    int bn = rem / gm;
    const int m0 = bm * 128, n0 = bn * 128;

    const int wm = (wave >> 1) * 64, wn = (wave & 1) * 64;
    const int lr = lane & 15;
    // read col slot: logical (lane>>4) XOR f(row); f=(row>>1)&3, row≡lr mod 16
    const int ka = (((lane >> 4) ^ ((lane >> 1) & 3)) * 8);

    // staging: lane fills LDS linearly at elem tid*8 (row tid>>2, slot tid&3);
    // fetches logical slot (tid&3) ^ f(row), f(row)=(tid>>3)&3
    const int srow = tid >> 2;
    const int scol = (((tid & 3) ^ ((tid >> 3) & 3)) * 8);
    const unsigned short* gA0h = Ahi + (size_t)(m0 + srow) * lda + scol;
    const unsigned short* gA1h = gA0h + (size_t)64 * lda;
    const unsigned short* gA0l = Alo + (size_t)(m0 + srow) * lda + scol;
    const unsigned short* gA1l = gA0l + (size_t)64 * lda;
    const unsigned short* gB0h = Bhi + (size_t)(n0 + srow) * ldb + scol;
    const unsigned short* gB1h = gB0h + (size_t)64 * ldb;
    const unsigned short* gB0l = Blo + (size_t)(n0 + srow) * ldb + scol;
    const unsigned short* gB1l = gB0l + (size_t)64 * ldb;
    const int lds0 = wave * 512;        // wave-uniform base; lanes land at +lane*8
    const int lds1 = 2048 + wave * 512; // rows 64..127

    f32x4 acc[4][4];
    #pragma unroll
    for (int i = 0; i < 4; i++)
        #pragma unroll
        for (int j = 0; j < 4; j++) acc[i][j] = (f32x4){0.f, 0.f, 0.f, 0.f};

    for (int k = 0; k < K; k += 32) {
        __syncthreads();
        GLL(gA0h + k, &lsAh[lds0]);
        GLL(gA1h + k, &lsAh[lds1]);
        GLL(gA0l + k, &lsAl[lds0]);
        GLL(gA1l + k, &lsAl[lds1]);
        GLL(gB0h + k, &lsBh[lds0]);
        GLL(gB1h + k, &lsBh[lds1]);
        GLL(gB0l + k, &lsBl[lds0]);
        GLL(gB1l + k, &lsBl[lds1]);
        __syncthreads();

        short8 a_[4], b_[4], t_[4];
        #pragma unroll
        for (int i = 0; i < 4; i++) {
            a_[i] = *(const short8*)&lsAh[(wm + i * 16 + lr) * 32 + ka];
            b_[i] = *(const short8*)&lsBh[(wn + i * 16 + lr) * 32 + ka];
        }
        // Ah * Bh
        #pragma unroll
        for (int i = 0; i < 4; i++)
            #pragma unroll
            for (int j = 0; j < 4; j++)
                acc[i][j] = __builtin_amdgcn_mfma_f32_16x16x32_bf16(a_[i], b_[j], acc[i][j], 0, 0, 0);
        // Ah * Bl
        #pragma unroll
        for (int i = 0; i < 4; i++) t_[i] = *(const short8*)&lsBl[(wn + i * 16 + lr) * 32 + ka];
        #pragma unroll
        for (int i = 0; i < 4; i++)
            #pragma unroll
            for (int j = 0; j < 4; j++)
                acc[i][j] = __builtin_amdgcn_mfma_f32_16x16x32_bf16(a_[i], t_[j], acc[i][j], 0, 0, 0);
        // Al * Bh (Al overwrites Ah regs — Ah dead now)
        #pragma unroll
        for (int i = 0; i < 4; i++) a_[i] = *(const short8*)&lsAl[(wm + i * 16 + lr) * 32 + ka];
        #pragma unroll
        for (int i = 0; i < 4; i++)
            #pragma unroll
            for (int j = 0; j < 4; j++)
                acc[i][j] = __builtin_amdgcn_mfma_f32_16x16x32_bf16(a_[i], b_[j], acc[i][j], 0, 0, 0);
    }

    // epilogue: D frag layout col=lane&15, row=(lane>>4)*4+q  [m89-verified]
    const int orow = m0 + wm + (lane >> 4) * 4;
    const int ocol = n0 + wn + lr;
    #pragma unroll
    for (int j = 0; j < 4; j++) {
        int col = ocol + j * 16;
        float bv = bias ? bias[col] : 0.f;
        #pragma unroll
        for (int i = 0; i < 4; i++) {
            #pragma unroll
            for (int q = 0; q < 4; q++) {
                int row = orow + i * 16 + q;
                float x = acc[i][j][q] + bv;
                if (ACC) x += Cf[(size_t)row * ldc + col];
                if (RELU) x = fmaxf(x, 0.f);
                if (BF16OUT) {
                    unsigned short h_, l_; split2(x, &h_, &l_);
                    Chi[(size_t)row * ldc + col] = h_;
                    Clo[(size_t)row * ldc + col] = l_;
                } else {
                    Cf[(size_t)row * ldc + col] = x;
                }
            }
        }
    }
}

// ---------------------------------------------------------------------------
// LayerNorm + GRU gate fusion. One block per row.
// gsum[:,0:1024]=gi_r+gh_r, gsum[:,1024:2048]=gi_u+gh_u, gsum[:,2048:3072]=gh_n
// gin[Bc,1024]=gi_n.  n_in = gi_n + reset*gh_n.
// Writes h (fp32, into hout) and he[:, :1024] hi/lo.
// ---------------------------------------------------------------------------
__device__ __forceinline__ float block_sum(float v, float* red, int tid) {
    #pragma unroll
    for (int m = 32; m >= 1; m >>= 1) v += __shfl_xor(v, m, 64);
    __syncthreads();
    if ((tid & 63) == 0) red[tid >> 6] = v;
    __syncthreads();
    return red[0] + red[1] + red[2] + red[3];
}

__global__ __launch_bounds__(256) void ln_gru(
    const float* __restrict__ gsum, const float* __restrict__ ginb,
    const float* __restrict__ deter, const float* __restrict__ mask,
    const float* __restrict__ grg, const float* __restrict__ grb,
    const float* __restrict__ gug, const float* __restrict__ gub,
    const float* __restrict__ gng, const float* __restrict__ gnb,
    float* __restrict__ hout, unsigned short* __restrict__ hehi, unsigned short* __restrict__ helo) {
    __shared__ float red[4];
    const int b = blockIdx.x, tid = threadIdx.x;
    const float* gr = gsum + (size_t)b * 3072;
    const float mk = mask[b];
    float r[4], u[4], gin[4], ghn[4], dm[4];
    int c[4];
    #pragma unroll
    for (int j = 0; j < 4; j++) {
        c[j] = tid + 256 * j;
        r[j] = gr[c[j]];
        u[j] = gr[1024 + c[j]];
        ghn[j] = gr[2048 + c[j]];
        gin[j] = ginb[(size_t)b * 1024 + c[j]];
        dm[j] = deter[(size_t)b * 1024 + c[j]] * mk;
    }
    const float inv = 1.f / 1024.f;

    // LN(r) -> reset
    float mr = block_sum(r[0] + r[1] + r[2] + r[3], red, tid) * inv;
    float vr;
    {
        float d0 = r[0] - mr, d1 = r[1] - mr, d2 = r[2] - mr, d3 = r[3] - mr;
        vr = block_sum(d0 * d0 + d1 * d1 + d2 * d2 + d3 * d3, red, tid) * inv;
    }
    float sr = rsqrtf(vr + 1e-3f);
    float reset[4];
    #pragma unroll
    for (int j = 0; j < 4; j++) {
        float y = (r[j] - mr) * sr * grg[c[j]] + grb[c[j]];
        reset[j] = 1.f / (1.f + expf(-y));
    }

    // LN(u) -> update
    float mu = block_sum(u[0] + u[1] + u[2] + u[3], red, tid) * inv;
    float vu;
    {
        float d0 = u[0] - mu, d1 = u[1] - mu, d2 = u[2] - mu, d3 = u[3] - mu;
        vu = block_sum(d0 * d0 + d1 * d1 + d2 * d2 + d3 * d3, red, tid) * inv;
    }
    float su = rsqrtf(vu + 1e-3f);
    float upd[4];
    #pragma unroll
    for (int j = 0; j < 4; j++) {
        float y = (u[j] - mu) * su * gug[c[j]] + gub[c[j]];
        upd[j] = 1.f / (1.f + expf(-y));
    }

    // n_in = gi_n + reset*gh_n ; LN(n) -> newval
    float nin[4];
    #pragma unroll
    for (int j = 0; j < 4; j++) nin[j] = gin[j] + reset[j] * ghn[j];
    float mn = block_sum(nin[0] + nin[1] + nin[2] + nin[3], red, tid) * inv;
    float vn;
    {
        float d0 = nin[0] - mn, d1 = nin[1] - mn, d2 = nin[2] - mn, d3 = nin[3] - mn;
        vn = block_sum(d0 * d0 + d1 * d1 + d2 * d2 + d3 * d3, red, tid) * inv;
    }
    float sn = rsqrtf(vn + 1e-3f);
    #pragma unroll
    for (int j = 0; j < 4; j++) {
        float y = (nin[j] - mn) * sn * gng[c[j]] + gnb[c[j]];
        float nv = tanhf(y);
        float h = upd[j] * nv + (1.f - upd[j]) * dm[j];
        hout[(size_t)b * 1024 + c[j]] = h;
        unsigned short hh, hl; split2(h, &hh, &hl);
        size_t o = (size_t)b * 2560 + c[j];
        hehi[o] = hh;
        helo[o] = hl;
    }
}

// ---------------------------------------------------------------------------
// Head2: out[b,64] = a[b,:1024] @ w[64,1024]^T + bias, then mean/std epilogue.
// 8 rows per block; a reconstructed from hi/lo into LDS; w streamed (L2-hot).
// Output pointers pre-offset to chunk.
// ---------------------------------------------------------------------------
__global__ __launch_bounds__(256) void head2(
    const unsigned short* __restrict__ ahi, const unsigned short* __restrict__ alo,
    const float* __restrict__ w, const float* __restrict__ bias,
    float* __restrict__ omean, float* __restrict__ ostd, float* __restrict__ olat) {
    __shared__ float arow[8 * 1024];
    const int tid = threadIdx.x;
    const size_t base = (size_t)blockIdx.x * 8 * 1024;
    for (int i = tid; i < 8 * 1024; i += 256)
        arow[i] = bf2f(ahi[base + i]) + bf2f(alo[base + i]);
    __syncthreads();

    const int j = tid & 63, rq = tid >> 6; // rows rq, rq+4
    float acc0 = 0.f, acc1 = 0.f;
    const float* wr = w + (size_t)j * 1024;
    for (int k = 0; k < 1024; k += 4) {
        float4 wv = *(const float4*)(wr + k);
        const float* a0 = &arow[rq * 1024 + k];
        const float* a1 = &arow[(rq + 4) * 1024 + k];
        acc0 += a0[0] * wv.x + a0[1] * wv.y + a0[2] * wv.z + a0[3] * wv.w;
        acc1 += a1[0] * wv.x + a1[1] * wv.y + a1[2] * wv.z + a1[3] * wv.w;
    }
    const float bv = bias[j];
    const int rbase = blockIdx.x * 8;
    float accs[2] = {acc0, acc1};
    #pragma unroll
    for (int t = 0; t < 2; t++) {
        int row = rbase + rq + 4 * t;
        float val = accs[t] + bv;
        if (j < 32) {
            omean[(size_t)row * 32 + j] = val;
            if (olat) olat[(size_t)row * 32 + j] = val;
        } else {
            float sp = fmaxf(val, 0.f) + log1pf(expf(-fabsf(val))) + 0.1f;
            ostd[(size_t)row * 32 + (j - 32)] = sp;
        }
    }
}

// ---------------------------------------------------------------------------
static inline size_t rup(size_t x) { return (x + 255) & ~(size_t)255; }

extern "C" void kernel_launch(void* const* d_in, const int* in_sizes, int n_in,
                              void* d_out, int out_size, void* d_ws, size_t ws_size,
                              hipStream_t stream) {
    const float* embedding = (const float*)d_in[0];
    const float* action    = (const float*)d_in[1];
    const float* mask      = (const float*)d_in[2];
    const float* deter     = (const float*)d_in[3];
    const float* stoc      = (const float*)d_in[4];
    const float* w_pre     = (const float*)d_in[5];
    const float* b_pre     = (const float*)d_in[6];
    const float* w_ih      = (const float*)d_in[7];
    const float* w_hh      = (const float*)d_in[8];
    const float* ln_r_g    = (const float*)d_in[9];
    const float* ln_r_b    = (const float*)d_in[10];
    const float* ln_u_g    = (const float*)d_in[11];
    const float* ln_u_b    = (const float*)d_in[12];
    const float* ln_n_g    = (const float*)d_in[13];
    const float* ln_n_b    = (const float*)d_in[14];
    const float* wp1       = (const float*)d_in[15];
    const float* bp1       = (const float*)d_in[16];
    const float* wp2       = (const float*)d_in[17];
    const float* bp2       = (const float*)d_in[18];
    const float* wq1       = (const float*)d_in[19];
    const float* bq1       = (const float*)d_in[20];
    const float* wq2       = (const float*)d_in[21];
    const float* bq2       = (const float*)d_in[22];
    float* out = (float*)d_out;

    // ---- workspace budget: weights (persistent) + per-chunk activations ----
    const size_t wbytes =
        2 * rup((size_t)65536 * 2) +          // wpre hi/lo
        4 * rup((size_t)3072 * 1024 * 2) +    // wih, whh hi/lo
        2 * rup((size_t)1024 * 1024 * 2) +    // wp1 hi/lo
        2 * rup((size_t)1024 * 2560 * 2);     // wq1 hi/lo
    int NCH = 16;
    {
        const int cands[5] = {1, 2, 4, 8, 16};
        for (int ci = 0; ci < 5; ci++) {
            size_t Bc = (size_t)BB / cands[ci];
            // sa(256) + x(4096) + d(4096) + gh(12288) + he(10240) bytes/row
            size_t need = wbytes + Bc * 30976 + (1u << 20);
            if (need <= ws_size) { NCH = cands[ci]; break; }
        }
    }
    const int Bc = BB / NCH;
    const int nbm = Bc / 128;
    const int gm = nbm < 32 ? nbm : 32;

    char* p = (char*)d_ws;
    auto alloc = [&](size_t bytes) { char* r = p; p += rup(bytes); return r; };
    unsigned short* wpre_hi = (unsigned short*)alloc((size_t)65536 * 2);
    unsigned short* wpre_lo = (unsigned short*)alloc((size_t)65536 * 2);
    unsigned short* wih_hi  = (unsigned short*)alloc((size_t)3072 * 1024 * 2);
    unsigned short* wih_lo  = (unsigned short*)alloc((size_t)3072 * 1024 * 2);
    unsigned short* whh_hi  = (unsigned short*)alloc((size_t)3072 * 1024 * 2);
    unsigned short* whh_lo  = (unsigned short*)alloc((size_t)3072 * 1024 * 2);
    unsigned short* wp1_hi  = (unsigned short*)alloc((size_t)1024 * 1024 * 2);
    unsigned short* wp1_lo  = (unsigned short*)alloc((size_t)1024 * 1024 * 2);
    unsigned short* wq1_hi  = (unsigned short*)alloc((size_t)1024 * 2560 * 2);
    unsigned short* wq1_lo  = (unsigned short*)alloc((size_t)1024 * 2560 * 2);
    unsigned short* sa_hi   = (unsigned short*)alloc((size_t)Bc * 64 * 2);
    unsigned short* sa_lo   = (unsigned short*)alloc((size_t)Bc * 64 * 2);
    unsigned short* xh      = (unsigned short*)alloc((size_t)Bc * 1024 * 2);
    unsigned short* xl      = (unsigned short*)alloc((size_t)Bc * 1024 * 2);
    unsigned short* dh      = (unsigned short*)alloc((size_t)Bc * 1024 * 2);
    unsigned short* dl      = (unsigned short*)alloc((size_t)Bc * 1024 * 2);
    float* gh_buf           = (float*)alloc((size_t)Bc * 3072 * 4);
    unsigned short* he_hi   = (unsigned short*)alloc((size_t)Bc * 2560 * 2);
    unsigned short* he_lo   = (unsigned short*)alloc((size_t)Bc * 2560 * 2);
    (void)dl;
    // aliases into dead regions:
    float* gin = (float*)dh;  // d (hi+lo contiguous, Bc*4096 B) dead after Gh
    unsigned short* p1_hi = (unsigned short*)gh_buf;  // gh dead after ln_gru
    unsigned short* p1_lo = p1_hi + (size_t)Bc * 1024;
    unsigned short* q1_hi = p1_lo + (size_t)Bc * 1024;
    unsigned short* q1_lo = q1_hi + (size_t)Bc * 1024;

    // --- weight conversions (once per call) ---
    split_wpre<<<256, 256, 0, stream>>>(w_pre, wpre_hi, wpre_lo);
    split_weights<<<9728, 256, 0, stream>>>(
        w_ih, wih_hi, wih_lo, w_hh, whh_hi, whh_lo,
        wp1, wp1_hi, wp1_lo, wq1, wq1_hi, wq1_lo);

    for (int ch = 0; ch < NCH; ch++) {
        const size_t r0 = (size_t)ch * Bc;

        split_sa<<<Bc / 4, 256, 0, stream>>>(
            stoc + r0 * 32, action + r0 * 12, mask + r0, sa_hi, sa_lo);
        split_embed<<<dim3(6, Bc), 256, 0, stream>>>(
            embedding + r0 * 1536, he_hi, he_lo);
        split_deter<<<dim3(4, Bc), 256, 0, stream>>>(
            deter + r0 * 1024, mask + r0, dh, dl);

        // G_pre: x = relu(sa @ w_pre^T + b_pre)
        gemm_hl<1, 1, 0><<<nbm * 8, 256, 0, stream>>>(
            sa_hi, sa_lo, 64, wpre_hi, wpre_lo, 64, b_pre,
            nullptr, xh, xl, 1024, 64, 8, gm);

        // Gh: gh = (deter*mask) @ w_hh^T  [Bc,3072]
        gemm_hl<0, 0, 0><<<nbm * 24, 256, 0, stream>>>(
            dh, dl, 1024, whh_hi, whh_lo, 1024, nullptr,
            gh_buf, nullptr, nullptr, 3072, 1024, 24, gm);

        // Gi_ru: gh[:,0:2048] += x @ w_ih[0:2048]^T
        gemm_hl<0, 0, 1><<<nbm * 16, 256, 0, stream>>>(
            xh, xl, 1024, wih_hi, wih_lo, 1024, nullptr,
            gh_buf, nullptr, nullptr, 3072, 1024, 16, gm);

        // Gi_n: gin = x @ w_ih[2048:3072]^T  (gin aliases dead d-region)
        gemm_hl<0, 0, 0><<<nbm * 8, 256, 0, stream>>>(
            xh, xl, 1024, wih_hi + (size_t)2048 * 1024, wih_lo + (size_t)2048 * 1024, 1024,
            nullptr, gin, nullptr, nullptr, 1024, 1024, 8, gm);

        // LN + GRU gating -> h (d_out @ B*128 + r0*1024) and he[:, :1024]
        ln_gru<<<Bc, 256, 0, stream>>>(
            gh_buf, gin, deter + r0 * 1024, mask + r0,
            ln_r_g, ln_r_b, ln_u_g, ln_u_b, ln_n_g, ln_n_b,
            out + (size_t)BB * 128 + r0 * 1024, he_hi, he_lo);

        // G3: p1 = relu(h @ wp1^T + bp1)   (p1 aliases dead gh)
        gemm_hl<1, 1, 0><<<nbm * 8, 256, 0, stream>>>(
            he_hi, he_lo, 2560, wp1_hi, wp1_lo, 1024, bp1,
            nullptr, p1_hi, p1_lo, 1024, 1024, 8, gm);

        // G4: q1 = relu([h|embedding] @ wq1^T + bq1)
        gemm_hl<1, 1, 0><<<nbm * 8, 256, 0, stream>>>(
            he_hi, he_lo, 2560, wq1_hi, wq1_lo, 2560, bq1,
            nullptr, q1_hi, q1_lo, 1024, 2560, 8, gm);

        // heads: out floats: post_mean@0, post_std@B*32, prior_mean@B*64,
        // prior_std@B*96, h@B*128, post_latent@B*1152
        head2<<<Bc / 8, 256, 0, stream>>>(p1_hi, p1_lo, wp2, bp2,
            out + (size_t)BB * 64 + r0 * 32, out + (size_t)BB * 96 + r0 * 32, nullptr);
        head2<<<Bc / 8, 256, 0, stream>>>(q1_hi, q1_lo, wq2, bq2,
            out + r0 * 32, out + (size_t)BB * 32 + r0 * 32,
            out + (size_t)BB * 1152 + r0 * 32);
    }
}

// Round 6
// 1872.876 us; speedup vs baseline: 1.0509x; 1.0509x over previous
//
#include <hip/hip_runtime.h>
#include <hip/hip_bf16.h>
#include <cstdint>

#define BB 16384
// EMBED 1536, DETER 1024, STOC 32, HID 1024, ACT 12, DIST 64

typedef __attribute__((ext_vector_type(8))) short short8;
typedef __attribute__((ext_vector_type(4))) float f32x4;

__device__ __forceinline__ unsigned short f2bf(float x) {
    uint32_t u = __float_as_uint(x);
    u += 0x7FFFu + ((u >> 16) & 1u);
    return (unsigned short)(u >> 16);
}
__device__ __forceinline__ float bf2f(unsigned short b) {
    return __uint_as_float(((uint32_t)b) << 16);
}
__device__ __forceinline__ void split2(float x, unsigned short* hi, unsigned short* lo) {
    unsigned short h = f2bf(x);
    *hi = h;
    *lo = f2bf(x - bf2f(h));
}

#define GLL(gp, lp) __builtin_amdgcn_global_load_lds( \
    (const __attribute__((address_space(1))) void*)(gp), \
    (__attribute__((address_space(3))) void*)(lp), 16, 0, 0)

// ---------------------------------------------------------------------------
// Split/convert kernels (fp32 -> bf16 hi/lo pairs)
// ---------------------------------------------------------------------------

// sa = [stoc*mask | action | 0pad] -> [Bc,64]  (pointers pre-offset to chunk)
__global__ __launch_bounds__(256) void split_sa(
    const float* __restrict__ stoc, const float* __restrict__ action,
    const float* __restrict__ mask,
    unsigned short* __restrict__ hi, unsigned short* __restrict__ lo) {
    int tid = threadIdx.x;
    int r = blockIdx.x * 4 + (tid >> 6);
    int c = tid & 63;
    float v = 0.f;
    if (c < 32) v = stoc[(size_t)r * 32 + c] * mask[r];
    else if (c < 44) v = action[(size_t)r * 12 + (c - 32)];
    size_t o = (size_t)r * 64 + c;
    unsigned short h, l; split2(v, &h, &l);
    hi[o] = h; lo[o] = l;
}

// w_pre [1024,44] -> [1024,64] zero-padded
__global__ __launch_bounds__(256) void split_wpre(
    const float* __restrict__ w, unsigned short* __restrict__ hi, unsigned short* __restrict__ lo) {
    int idx = blockIdx.x * 256 + threadIdx.x; // < 65536
    int row = idx >> 6, c = idx & 63;
    float v = (c < 44) ? w[row * 44 + c] : 0.f;
    unsigned short h, l; split2(v, &h, &l);
    hi[idx] = h; lo[idx] = l;
}

// merged flat float4 split of the 4 big weights (segments in blocks):
// [0,3072) w_ih, [3072,6144) w_hh, [6144,7168) wp1, [7168,9728) wq1
__global__ __launch_bounds__(256) void split_weights(
    const float* __restrict__ w0, unsigned short* __restrict__ h0, unsigned short* __restrict__ l0,
    const float* __restrict__ w1, unsigned short* __restrict__ h1, unsigned short* __restrict__ l1,
    const float* __restrict__ w2, unsigned short* __restrict__ h2, unsigned short* __restrict__ l2,
    const float* __restrict__ w3, unsigned short* __restrict__ h3, unsigned short* __restrict__ l3) {
    int b = blockIdx.x;
    const float* src; unsigned short* hi; unsigned short* lo; int lb;
    if (b < 3072)      { src = w0; hi = h0; lo = l0; lb = b; }
    else if (b < 6144) { src = w1; hi = h1; lo = l1; lb = b - 3072; }
    else if (b < 7168) { src = w2; hi = h2; lo = l2; lb = b - 6144; }
    else               { src = w3; hi = h3; lo = l3; lb = b - 7168; }
    size_t i4 = (size_t)lb * 256 + threadIdx.x;
    float4 v = ((const float4*)src)[i4];
    ushort4 h, l;
    split2(v.x, &h.x, &l.x);
    split2(v.y, &h.y, &l.y);
    split2(v.z, &h.z, &l.z);
    split2(v.w, &h.w, &l.w);
    ((ushort4*)hi)[i4] = h;
    ((ushort4*)lo)[i4] = l;
}

// embedding [Bc,1536] -> he[:, 1024:2560]  (e pre-offset)
__global__ __launch_bounds__(256) void split_embed(
    const float* __restrict__ e, unsigned short* __restrict__ hi, unsigned short* __restrict__ lo) {
    int b = blockIdx.y;
    int c = blockIdx.x * 256 + threadIdx.x; // < 1536
    float v = e[(size_t)b * 1536 + c];
    size_t o = (size_t)b * 2560 + 1024 + c;
    unsigned short h, l; split2(v, &h, &l);
    hi[o] = h; lo[o] = l;
}

// deter*mask [Bc,1024] -> dh/dl  (pointers pre-offset)
__global__ __launch_bounds__(256) void split_deter(
    const float* __restrict__ dt, const float* __restrict__ mask,
    unsigned short* __restrict__ hi, unsigned short* __restrict__ lo) {
    int b = blockIdx.y;
    int c = blockIdx.x * 256 + threadIdx.x; // < 1024
    float v = dt[(size_t)b * 1024 + c] * mask[b];
    size_t o = (size_t)b * 1024 + c;
    unsigned short h, l; split2(v, &h, &l);
    hi[o] = h; lo[o] = l;
}

// ---------------------------------------------------------------------------
// Multi-phase split-bf16 MFMA GEMM (T2+T3+T4+T5 schedule).
// C[M,N] = act(A[M,K] @ B[N,K]^T + bias [+ C_prev])
// BM=256, BN=128, BK=32. 512 threads = 8 waves (4m x 2n), wave out 64x64
// (4x4 frags of 16x16x32). 3-product scheme: C = Ah*Bh + Ah*Bl + Al*Bh.
//
// LDS: 3 buffers x 48KB (Ah[256][32] Al[256][32] Bh[128][32] Bl[128][32]).
// 2-tile-deep prefetch: 6 global_load_lds per tile, issued 2 per phase for
// tile t+2 while computing tile t; top-of-tile s_waitcnt vmcnt(6) (never 0
// in the main loop — T4). 3 phases per tile, one per product, each
// {ds_read subtile | 2 GLL -> barrier -> setprio(1) 16 MFMA setprio(0)
//  -> barrier}. Only the top-of-tile vmcnt+barrier is correctness-critical
// (asm "memory" clobber is the compiler fence; barrier makes the per-wave
// vmcnt guarantee cross-wave). WAR-safe: tile t+2's DMA target buffer was
// last read at tile t-1, fully consumed before this tile began.
//
// T2 swizzle (both-sides, rule 21): physical slot = logical ^ ((row>>1)&3),
// applied to global source col (staging) and LDS read col. Max 2-way (free).
// ---------------------------------------------------------------------------
template<int RELU, int BF16OUT, int ACC>
__global__ __launch_bounds__(512, 2) void gemm_mp(
    const unsigned short* __restrict__ Ahi, const unsigned short* __restrict__ Alo, int lda,
    const unsigned short* __restrict__ Bhi, const unsigned short* __restrict__ Blo, int ldb,
    const float* __restrict__ bias,
    float* __restrict__ Cf, unsigned short* __restrict__ Chi, unsigned short* __restrict__ Clo,
    int ldc, int K, int nbn, int gm) {
    __shared__ unsigned short sm[3 * 24576];  // 144 KB

    const int tid = threadIdx.x;
    const int wave = tid >> 6, lane = tid & 63;

    int bid = blockIdx.x;
    int group = bid / (gm * nbn);
    int rem = bid % (gm * nbn);
    int bm = group * gm + (rem % gm);
    int bn = rem / gm;
    const int m0 = bm * 256, n0 = bn * 128;

    const int wm = (wave >> 1) * 64, wn = (wave & 1) * 64;
    const int lr = lane & 15;
    const int ka = (((lane >> 4) ^ ((lane >> 1) & 3)) * 8);

    // staging: thread covers row tid>>2 (128 rows per GLL call), phys slot tid&3
    const int srow = tid >> 2;
    const int scol = (((tid & 3) ^ ((tid >> 3) & 3)) * 8);
    const unsigned short* gA0h = Ahi + (size_t)(m0 + srow) * lda + scol;
    const unsigned short* gA1h = gA0h + (size_t)128 * lda;
    const unsigned short* gA0l = Alo + (size_t)(m0 + srow) * lda + scol;
    const unsigned short* gA1l = gA0l + (size_t)128 * lda;
    const unsigned short* gB0h = Bhi + (size_t)(n0 + srow) * ldb + scol;
    const unsigned short* gB0l = Blo + (size_t)(n0 + srow) * ldb + scol;

    const int wofs = wave * 512;  // elems; each wave's lanes land at +lane*8
    // stream elem offsets in a buffer: Ah 0, Al 8192, Bh 16384, Bl 20480

    f32x4 acc[4][4];
    #pragma unroll
    for (int i = 0; i < 4; i++)
        #pragma unroll
        for (int j = 0; j < 4; j++) acc[i][j] = (f32x4){0.f, 0.f, 0.f, 0.f};

    const int nt = K >> 5;  // >= 2 always (K >= 64)

    // prologue: stage tiles 0 (buf0) and 1 (buf1) — 12 loads in flight
    {
        unsigned short* b0 = sm;
        unsigned short* b1 = sm + 24576;
        GLL(gA0h, &b0[wofs]);
        GLL(gA1h, &b0[4096 + wofs]);
        GLL(gA0l, &b0[8192 + wofs]);
        GLL(gA1l, &b0[12288 + wofs]);
        GLL(gB0h, &b0[16384 + wofs]);
        GLL(gB0l, &b0[20480 + wofs]);
        GLL(gA0h + 32, &b1[wofs]);
        GLL(gA1h + 32, &b1[4096 + wofs]);
        GLL(gA0l + 32, &b1[8192 + wofs]);
        GLL(gA1l + 32, &b1[12288 + wofs]);
        GLL(gB0h + 32, &b1[16384 + wofs]);
        GLL(gB0l + 32, &b1[20480 + wofs]);
    }

    int cur = 0;
    for (int t = 0; t < nt; t++) {
        // tile t ready; leave tile t+1's 6 loads in flight (T4: counted, not 0)
        if (t + 1 < nt) asm volatile("s_waitcnt vmcnt(6)" ::: "memory");
        else            asm volatile("s_waitcnt vmcnt(0)" ::: "memory");
        __builtin_amdgcn_s_barrier();

        unsigned short* cb = sm + cur * 24576;
        unsigned short* nb = sm + ((cur + 2) % 3) * 24576;
        const int kpre = (t + 2) * 32;
        const bool pf = (t + 2) < nt;

        short8 a_[4], b_[4], t_[4];

        // ---- phase 1: Ah * Bh ----
        #pragma unroll
        for (int i = 0; i < 4; i++) {
            a_[i] = *(const short8*)&cb[(wm + i * 16 + lr) * 32 + ka];
            b_[i] = *(const short8*)&cb[16384 + (wn + i * 16 + lr) * 32 + ka];
        }
        if (pf) { GLL(gA0h + kpre, &nb[wofs]); GLL(gA1h + kpre, &nb[4096 + wofs]); }
        __builtin_amdgcn_s_barrier();
        __builtin_amdgcn_s_setprio(1);
        #pragma unroll
        for (int i = 0; i < 4; i++)
            #pragma unroll
            for (int j = 0; j < 4; j++)
                acc[i][j] = __builtin_amdgcn_mfma_f32_16x16x32_bf16(a_[i], b_[j], acc[i][j], 0, 0, 0);
        __builtin_amdgcn_s_setprio(0);
        __builtin_amdgcn_s_barrier();

        // ---- phase 2: Ah * Bl ----
        #pragma unroll
        for (int j = 0; j < 4; j++)
            t_[j] = *(const short8*)&cb[20480 + (wn + j * 16 + lr) * 32 + ka];
        if (pf) { GLL(gA0l + kpre, &nb[8192 + wofs]); GLL(gA1l + kpre, &nb[12288 + wofs]); }
        __builtin_amdgcn_s_barrier();
        __builtin_amdgcn_s_setprio(1);
        #pragma unroll
        for (int i = 0; i < 4; i++)
            #pragma unroll
            for (int j = 0; j < 4; j++)
                acc[i][j] = __builtin_amdgcn_mfma_f32_16x16x32_bf16(a_[i], t_[j], acc[i][j], 0, 0, 0);
        __builtin_amdgcn_s_setprio(0);
        __builtin_amdgcn_s_barrier();

        // ---- phase 3: Al * Bh (Al overwrites Ah regs) ----
        #pragma unroll
        for (int i = 0; i < 4; i++)
            a_[i] = *(const short8*)&cb[8192 + (wm + i * 16 + lr) * 32 + ka];
        if (pf) { GLL(gB0h + kpre, &nb[16384 + wofs]); GLL(gB0l + kpre, &nb[20480 + wofs]); }
        __builtin_amdgcn_s_barrier();
        __builtin_amdgcn_s_setprio(1);
        #pragma unroll
        for (int i = 0; i < 4; i++)
            #pragma unroll
            for (int j = 0; j < 4; j++)
                acc[i][j] = __builtin_amdgcn_mfma_f32_16x16x32_bf16(a_[i], b_[j], acc[i][j], 0, 0, 0);
        __builtin_amdgcn_s_setprio(0);
        __builtin_amdgcn_s_barrier();

        cur = (cur + 1) % 3;
    }

    // epilogue: D frag layout col=lane&15, row=(lane>>4)*4+q  [m89-verified]
    const int orow = m0 + wm + (lane >> 4) * 4;
    const int ocol = n0 + wn + lr;
    #pragma unroll
    for (int j = 0; j < 4; j++) {
        int col = ocol + j * 16;
        float bv = bias ? bias[col] : 0.f;
        #pragma unroll
        for (int i = 0; i < 4; i++) {
            #pragma unroll
            for (int q = 0; q < 4; q++) {
                int row = orow + i * 16 + q;
                float x = acc[i][j][q] + bv;
                if (ACC) x += Cf[(size_t)row * ldc + col];
                if (RELU) x = fmaxf(x, 0.f);
                if (BF16OUT) {
                    unsigned short h_, l_; split2(x, &h_, &l_);
                    Chi[(size_t)row * ldc + col] = h_;
                    Clo[(size_t)row * ldc + col] = l_;
                } else {
                    Cf[(size_t)row * ldc + col] = x;
                }
            }
        }
    }
}

// ---------------------------------------------------------------------------
// LayerNorm + GRU gate fusion. One block per row.
// gsum[:,0:1024]=gi_r+gh_r, gsum[:,1024:2048]=gi_u+gh_u, gsum[:,2048:3072]=gh_n
// gin[Bc,1024]=gi_n.  n_in = gi_n + reset*gh_n.
// ---------------------------------------------------------------------------
__device__ __forceinline__ float block_sum(float v, float* red, int tid) {
    #pragma unroll
    for (int m = 32; m >= 1; m >>= 1) v += __shfl_xor(v, m, 64);
    __syncthreads();
    if ((tid & 63) == 0) red[tid >> 6] = v;
    __syncthreads();
    return red[0] + red[1] + red[2] + red[3];
}

__global__ __launch_bounds__(256) void ln_gru(
    const float* __restrict__ gsum, const float* __restrict__ ginb,
    const float* __restrict__ deter, const float* __restrict__ mask,
    const float* __restrict__ grg, const float* __restrict__ grb,
    const float* __restrict__ gug, const float* __restrict__ gub,
    const float* __restrict__ gng, const float* __restrict__ gnb,
    float* __restrict__ hout, unsigned short* __restrict__ hehi, unsigned short* __restrict__ helo) {
    __shared__ float red[4];
    const int b = blockIdx.x, tid = threadIdx.x;
    const float* gr = gsum + (size_t)b * 3072;
    const float mk = mask[b];
    float r[4], u[4], gin[4], ghn[4], dm[4];
    int c[4];
    #pragma unroll
    for (int j = 0; j < 4; j++) {
        c[j] = tid + 256 * j;
        r[j] = gr[c[j]];
        u[j] = gr[1024 + c[j]];
        ghn[j] = gr[2048 + c[j]];
        gin[j] = ginb[(size_t)b * 1024 + c[j]];
        dm[j] = deter[(size_t)b * 1024 + c[j]] * mk;
    }
    const float inv = 1.f / 1024.f;

    float mr = block_sum(r[0] + r[1] + r[2] + r[3], red, tid) * inv;
    float vr;
    {
        float d0 = r[0] - mr, d1 = r[1] - mr, d2 = r[2] - mr, d3 = r[3] - mr;
        vr = block_sum(d0 * d0 + d1 * d1 + d2 * d2 + d3 * d3, red, tid) * inv;
    }
    float sr = rsqrtf(vr + 1e-3f);
    float reset[4];
    #pragma unroll
    for (int j = 0; j < 4; j++) {
        float y = (r[j] - mr) * sr * grg[c[j]] + grb[c[j]];
        reset[j] = 1.f / (1.f + expf(-y));
    }

    float mu = block_sum(u[0] + u[1] + u[2] + u[3], red, tid) * inv;
    float vu;
    {
        float d0 = u[0] - mu, d1 = u[1] - mu, d2 = u[2] - mu, d3 = u[3] - mu;
        vu = block_sum(d0 * d0 + d1 * d1 + d2 * d2 + d3 * d3, red, tid) * inv;
    }
    float su = rsqrtf(vu + 1e-3f);
    float upd[4];
    #pragma unroll
    for (int j = 0; j < 4; j++) {
        float y = (u[j] - mu) * su * gug[c[j]] + gub[c[j]];
        upd[j] = 1.f / (1.f + expf(-y));
    }

    float nin[4];
    #pragma unroll
    for (int j = 0; j < 4; j++) nin[j] = gin[j] + reset[j] * ghn[j];
    float mn = block_sum(nin[0] + nin[1] + nin[2] + nin[3], red, tid) * inv;
    float vn;
    {
        float d0 = nin[0] - mn, d1 = nin[1] - mn, d2 = nin[2] - mn, d3 = nin[3] - mn;
        vn = block_sum(d0 * d0 + d1 * d1 + d2 * d2 + d3 * d3, red, tid) * inv;
    }
    float sn = rsqrtf(vn + 1e-3f);
    #pragma unroll
    for (int j = 0; j < 4; j++) {
        float y = (nin[j] - mn) * sn * gng[c[j]] + gnb[c[j]];
        float nv = tanhf(y);
        float h = upd[j] * nv + (1.f - upd[j]) * dm[j];
        hout[(size_t)b * 1024 + c[j]] = h;
        unsigned short hh, hl; split2(h, &hh, &hl);
        size_t o = (size_t)b * 2560 + c[j];
        hehi[o] = hh;
        helo[o] = hl;
    }
}

// ---------------------------------------------------------------------------
// Head2: out[b,64] = a[b,:1024] @ w[64,1024]^T + bias, mean/std epilogue.
// ---------------------------------------------------------------------------
__global__ __launch_bounds__(256) void head2(
    const unsigned short* __restrict__ ahi, const unsigned short* __restrict__ alo,
    const float* __restrict__ w, const float* __restrict__ bias,
    float* __restrict__ omean, float* __restrict__ ostd, float* __restrict__ olat) {
    __shared__ float arow[8 * 1024];
    const int tid = threadIdx.x;
    const size_t base = (size_t)blockIdx.x * 8 * 1024;
    for (int i = tid; i < 8 * 1024; i += 256)
        arow[i] = bf2f(ahi[base + i]) + bf2f(alo[base + i]);
    __syncthreads();

    const int j = tid & 63, rq = tid >> 6;
    float acc0 = 0.f, acc1 = 0.f;
    const float* wr = w + (size_t)j * 1024;
    for (int k = 0; k < 1024; k += 4) {
        float4 wv = *(const float4*)(wr + k);
        const float* a0 = &arow[rq * 1024 + k];
        const float* a1 = &arow[(rq + 4) * 1024 + k];
        acc0 += a0[0] * wv.x + a0[1] * wv.y + a0[2] * wv.z + a0[3] * wv.w;
        acc1 += a1[0] * wv.x + a1[1] * wv.y + a1[2] * wv.z + a1[3] * wv.w;
    }
    const float bv = bias[j];
    const int rbase = blockIdx.x * 8;
    float accs[2] = {acc0, acc1};
    #pragma unroll
    for (int t = 0; t < 2; t++) {
        int row = rbase + rq + 4 * t;
        float val = accs[t] + bv;
        if (j < 32) {
            omean[(size_t)row * 32 + j] = val;
            if (olat) olat[(size_t)row * 32 + j] = val;
        } else {
            float sp = fmaxf(val, 0.f) + log1pf(expf(-fabsf(val))) + 0.1f;
            ostd[(size_t)row * 32 + (j - 32)] = sp;
        }
    }
}

// ---------------------------------------------------------------------------
static inline size_t rup(size_t x) { return (x + 255) & ~(size_t)255; }

extern "C" void kernel_launch(void* const* d_in, const int* in_sizes, int n_in,
                              void* d_out, int out_size, void* d_ws, size_t ws_size,
                              hipStream_t stream) {
    const float* embedding = (const float*)d_in[0];
    const float* action    = (const float*)d_in[1];
    const float* mask      = (const float*)d_in[2];
    const float* deter     = (const float*)d_in[3];
    const float* stoc      = (const float*)d_in[4];
    const float* w_pre     = (const float*)d_in[5];
    const float* b_pre     = (const float*)d_in[6];
    const float* w_ih      = (const float*)d_in[7];
    const float* w_hh      = (const float*)d_in[8];
    const float* ln_r_g    = (const float*)d_in[9];
    const float* ln_r_b    = (const float*)d_in[10];
    const float* ln_u_g    = (const float*)d_in[11];
    const float* ln_u_b    = (const float*)d_in[12];
    const float* ln_n_g    = (const float*)d_in[13];
    const float* ln_n_b    = (const float*)d_in[14];
    const float* wp1       = (const float*)d_in[15];
    const float* bp1       = (const float*)d_in[16];
    const float* wp2       = (const float*)d_in[17];
    const float* bp2       = (const float*)d_in[18];
    const float* wq1       = (const float*)d_in[19];
    const float* bq1       = (const float*)d_in[20];
    const float* wq2       = (const float*)d_in[21];
    const float* bq2       = (const float*)d_in[22];
    float* out = (float*)d_out;

    // ---- workspace budget: weights (persistent) + per-chunk activations ----
    const size_t wbytes =
        2 * rup((size_t)65536 * 2) +
        4 * rup((size_t)3072 * 1024 * 2) +
        2 * rup((size_t)1024 * 1024 * 2) +
        2 * rup((size_t)1024 * 2560 * 2);
    int NCH = 16;
    {
        const int cands[5] = {1, 2, 4, 8, 16};
        for (int ci = 0; ci < 5; ci++) {
            size_t Bc = (size_t)BB / cands[ci];
            size_t need = wbytes + Bc * 30976 + (1u << 20);
            if (need <= ws_size) { NCH = cands[ci]; break; }
        }
    }
    const int Bc = BB / NCH;
    const int nbm = Bc / 256;                   // 256-row tiles
    const int gm = nbm < 16 ? nbm : 16;         // divides nbm (all pow2 >= 4)

    char* p = (char*)d_ws;
    auto alloc = [&](size_t bytes) { char* r = p; p += rup(bytes); return r; };
    unsigned short* wpre_hi = (unsigned short*)alloc((size_t)65536 * 2);
    unsigned short* wpre_lo = (unsigned short*)alloc((size_t)65536 * 2);
    unsigned short* wih_hi  = (unsigned short*)alloc((size_t)3072 * 1024 * 2);
    unsigned short* wih_lo  = (unsigned short*)alloc((size_t)3072 * 1024 * 2);
    unsigned short* whh_hi  = (unsigned short*)alloc((size_t)3072 * 1024 * 2);
    unsigned short* whh_lo  = (unsigned short*)alloc((size_t)3072 * 1024 * 2);
    unsigned short* wp1_hi  = (unsigned short*)alloc((size_t)1024 * 1024 * 2);
    unsigned short* wp1_lo  = (unsigned short*)alloc((size_t)1024 * 1024 * 2);
    unsigned short* wq1_hi  = (unsigned short*)alloc((size_t)1024 * 2560 * 2);
    unsigned short* wq1_lo  = (unsigned short*)alloc((size_t)1024 * 2560 * 2);
    unsigned short* sa_hi   = (unsigned short*)alloc((size_t)Bc * 64 * 2);
    unsigned short* sa_lo   = (unsigned short*)alloc((size_t)Bc * 64 * 2);
    unsigned short* xh      = (unsigned short*)alloc((size_t)Bc * 1024 * 2);
    unsigned short* xl      = (unsigned short*)alloc((size_t)Bc * 1024 * 2);
    unsigned short* dh      = (unsigned short*)alloc((size_t)Bc * 1024 * 2);
    unsigned short* dl      = (unsigned short*)alloc((size_t)Bc * 1024 * 2);
    float* gh_buf           = (float*)alloc((size_t)Bc * 3072 * 4);
    unsigned short* he_hi   = (unsigned short*)alloc((size_t)Bc * 2560 * 2);
    unsigned short* he_lo   = (unsigned short*)alloc((size_t)Bc * 2560 * 2);
    (void)dl;
    // aliases into dead regions:
    float* gin = (float*)dh;  // d (hi+lo contiguous, Bc*4096 B) dead after Gh
    unsigned short* p1_hi = (unsigned short*)gh_buf;  // gh dead after ln_gru
    unsigned short* p1_lo = p1_hi + (size_t)Bc * 1024;
    unsigned short* q1_hi = p1_lo + (size_t)Bc * 1024;
    unsigned short* q1_lo = q1_hi + (size_t)Bc * 1024;

    // --- weight conversions (once per call) ---
    split_wpre<<<256, 256, 0, stream>>>(w_pre, wpre_hi, wpre_lo);
    split_weights<<<9728, 256, 0, stream>>>(
        w_ih, wih_hi, wih_lo, w_hh, whh_hi, whh_lo,
        wp1, wp1_hi, wp1_lo, wq1, wq1_hi, wq1_lo);

    for (int ch = 0; ch < NCH; ch++) {
        const size_t r0 = (size_t)ch * Bc;

        split_sa<<<Bc / 4, 256, 0, stream>>>(
            stoc + r0 * 32, action + r0 * 12, mask + r0, sa_hi, sa_lo);
        split_embed<<<dim3(6, Bc), 256, 0, stream>>>(
            embedding + r0 * 1536, he_hi, he_lo);
        split_deter<<<dim3(4, Bc), 256, 0, stream>>>(
            deter + r0 * 1024, mask + r0, dh, dl);

        // G_pre: x = relu(sa @ w_pre^T + b_pre)
        gemm_mp<1, 1, 0><<<nbm * 8, 512, 0, stream>>>(
            sa_hi, sa_lo, 64, wpre_hi, wpre_lo, 64, b_pre,
            nullptr, xh, xl, 1024, 64, 8, gm);

        // Gh: gh = (deter*mask) @ w_hh^T  [Bc,3072]
        gemm_mp<0, 0, 0><<<nbm * 24, 512, 0, stream>>>(
            dh, dl, 1024, whh_hi, whh_lo, 1024, nullptr,
            gh_buf, nullptr, nullptr, 3072, 1024, 24, gm);

        // Gi_ru: gh[:,0:2048] += x @ w_ih[0:2048]^T
        gemm_mp<0, 0, 1><<<nbm * 16, 512, 0, stream>>>(
            xh, xl, 1024, wih_hi, wih_lo, 1024, nullptr,
            gh_buf, nullptr, nullptr, 3072, 1024, 16, gm);

        // Gi_n: gin = x @ w_ih[2048:3072]^T  (gin aliases dead d-region)
        gemm_mp<0, 0, 0><<<nbm * 8, 512, 0, stream>>>(
            xh, xl, 1024, wih_hi + (size_t)2048 * 1024, wih_lo + (size_t)2048 * 1024, 1024,
            nullptr, gin, nullptr, nullptr, 1024, 1024, 8, gm);

        // LN + GRU gating -> h (d_out @ B*128 + r0*1024) and he[:, :1024]
        ln_gru<<<Bc, 256, 0, stream>>>(
            gh_buf, gin, deter + r0 * 1024, mask + r0,
            ln_r_g, ln_r_b, ln_u_g, ln_u_b, ln_n_g, ln_n_b,
            out + (size_t)BB * 128 + r0 * 1024, he_hi, he_lo);

        // G3: p1 = relu(h @ wp1^T + bp1)   (p1 aliases dead gh)
        gemm_mp<1, 1, 0><<<nbm * 8, 512, 0, stream>>>(
            he_hi, he_lo, 2560, wp1_hi, wp1_lo, 1024, bp1,
            nullptr, p1_hi, p1_lo, 1024, 1024, 8, gm);

        // G4: q1 = relu([h|embedding] @ wq1^T + bq1)
        gemm_mp<1, 1, 0><<<nbm * 8, 512, 0, stream>>>(
            he_hi, he_lo, 2560, wq1_hi, wq1_lo, 2560, bq1,
            nullptr, q1_hi, q1_lo, 1024, 2560, 8, gm);

        // heads: out floats: post_mean@0, post_std@B*32, prior_mean@B*64,
        // prior_std@B*96, h@B*128, post_latent@B*1152
        head2<<<Bc / 8, 256, 0, stream>>>(p1_hi, p1_lo, wp2, bp2,
            out + (size_t)BB * 64 + r0 * 32, out + (size_t)BB * 96 + r0 * 32, nullptr);
        head2<<<Bc / 8, 256, 0, stream>>>(q1_hi, q1_lo, wq2, bq2,
            out + r0 * 32, out + (size_t)BB * 32 + r0 * 32,
            out + (size_t)BB * 1152 + r0 * 32);
    }
}